// Round 6
// baseline (400.792 us; speedup 1.0000x reference)
//
#include <hip/hip_runtime.h>
#include <cmath>

#define NB 4
#define CC 256
#define HW 4096
#define NQ 4   // loop-dim split per sweep (partials combined later)

static constexpr float kEPS = 1e-8f;
static constexpr float kSIG = 0.1f + 1e-8f;

typedef __attribute__((ext_vector_type(8)))  short short8;
typedef __attribute__((ext_vector_type(16))) float f32x16;

// workspace layout in floats
enum {
  OFF_MEAN = 0,                      // 256
  OFF_INVT = 256,                    // NB*HW
  OFF_INVI = OFF_INVT + NB*HW,       // NB*HW
  OFF_BETA = OFF_INVI + NB*HW,       // NB*HW
  OFF_AG   = OFF_BETA + NB*HW,       // NB*HW  (alpha, later overwritten with gamma)
  OFF_CMAX = OFF_AG   + NB*HW,       // NQ*NB*HW partials
  OFF_WSUM = OFF_CMAX + NQ*NB*HW,    // NQ*NB*HW partials
  OFF_MAXV = OFF_WSUM + NQ*NB*HW,    // NQ*NB*HW partials
  OFF_END_SMALL = OFF_MAXV + NQ*NB*HW,
  OFF_GT = OFF_END_SMALL,            // NB*HW*CC ushorts = NB*HW*CC/2 floats
  OFF_GI = OFF_GT + NB*HW*CC/2,
  WS_FLOATS_FULL = OFF_GI + NB*HW*CC/2
};

__device__ __forceinline__ float blkReduceSum(float v) {
  __shared__ float sh[4];
  const int lane = threadIdx.x & 63, w = threadIdx.x >> 6;
  #pragma unroll
  for (int o = 32; o > 0; o >>= 1) v += __shfl_down(v, o, 64);
  __syncthreads();
  if (lane == 0) sh[w] = v;
  __syncthreads();
  return sh[0] + sh[1] + sh[2] + sh[3];
}

__device__ __forceinline__ ushort f2bf(float x) {
  unsigned u = __float_as_uint(x);
  unsigned r = (u + 0x7fffu + ((u >> 16) & 1u)) >> 16;  // RNE
  return (ushort)r;
}

// K1: per-channel mean of featureT over (n, h, w). grid=256
__global__ __launch_bounds__(256) void k_mean(const float* __restrict__ fT,
                                              float* __restrict__ ws) {
  const int c = blockIdx.x, t = threadIdx.x;
  float s = 0.f;
  for (int n = 0; n < NB; ++n) {
    const float* p = fT + (size_t)(n*CC + c)*HW;
    #pragma unroll
    for (int k = 0; k < 16; ++k) s += p[k*256 + t];
  }
  const float tot = blkReduceSum(s);
  if (t == 0) ws[OFF_MEAN + c] = tot * (1.0f/16384.0f);
}

// K2: per-pixel inverse channel-norms for T and I. grid=256
__global__ __launch_bounds__(256) void k_norms(const float* __restrict__ fT,
                                               const float* __restrict__ fI,
                                               float* __restrict__ ws) {
  __shared__ float sT[4][64], sI[4][64];
  const int t = threadIdx.x, q = t & 63, a = t >> 6;
  const int n = blockIdx.x >> 6;
  const int q0 = (blockIdx.x & 63) * 64;
  const float* mean = ws + OFF_MEAN;
  float accT = 0.f, accI = 0.f;
  for (int i = 0; i < 64; ++i) {
    const int c = a*64 + i;
    const float m = mean[c];
    const size_t base = (size_t)(n*CC + c)*HW + q0 + q;
    const float vT = fT[base] - m; accT += vT*vT;
    const float vI = fI[base] - m; accI += vI*vI;
  }
  sT[a][q] = accT; sI[a][q] = accI;
  __syncthreads();
  if (t < 64) {
    const float ssT = sT[0][t] + sT[1][t] + sT[2][t] + sT[3][t];
    const float ssI = sI[0][t] + sI[1][t] + sI[2][t] + sI[3][t];
    ws[OFF_INVT + n*HW + q0 + t] = 1.0f/(sqrtf(ssT) + kEPS);
    ws[OFF_INVI + n*HW + q0 + t] = 1.0f/(sqrtf(ssI) + kEPS);
  }
}

// K3: normalize + transpose to bf16 [n][p][c]. grid = 2*NB*64*4 = 2048
__global__ __launch_bounds__(256) void k_prep(const float* __restrict__ fT,
                                              const float* __restrict__ fI,
                                              float* __restrict__ ws) {
  __shared__ float lds[64][65];      // [p][c]
  const int t = threadIdx.x;
  int bid = blockIdx.x;
  const int tensor = (bid >= 1024); bid &= 1023;
  const int n  = bid >> 8;
  const int pt = (bid & 255) >> 2;
  const int ct = bid & 3;
  const int p0 = pt * 64, c0 = ct * 64;

  const float* __restrict__ src = tensor ? fI : fT;
  const float* __restrict__ inv = ws + (tensor ? OFF_INVI : OFF_INVT);
  ushort* __restrict__ dst = (ushort*)(ws + (tensor ? OFF_GI : OFF_GT));

  const int pcol = t & 63, crb = t >> 6;
  const float invv = inv[n*HW + p0 + pcol];
  #pragma unroll
  for (int i = 0; i < 16; ++i) {
    const int cr = crb + 4*i;
    const float m = ws[OFF_MEAN + c0 + cr];
    const float v = src[((size_t)(n*CC + c0 + cr))*HW + p0 + pcol];
    lds[pcol][cr] = (v - m) * invv;
  }
  __syncthreads();
  const int cpi = t & 31, prb = t >> 5;
  #pragma unroll
  for (int j = 0; j < 8; ++j) {
    const int p = prb + 8*j;
    ushort2 u;
    u.x = f2bf(lds[p][2*cpi]);
    u.y = f2bf(lds[p][2*cpi + 1]);
    *(ushort2*)(dst + ((size_t)(n*HW + p0 + p))*CC + c0 + 2*cpi) = u;
  }
}

// ---------------- MFMA sweep (R6: software-prefetched A staging) ----------
// s[m][n] = sum_c gL[m][c] * gR[n][c]   (m = loop dim, n = resident dim)
// mode 0: gL=T(p), gR=I(q): colmax_q = max_m s
// mode 1: gL=T(p), gR=I(q): Wsum_q = sum_m exp(a_q + b_q s)   (params per n)
// mode 2: gL=I(q), gR=T(p): maxv_p = max_m (g_m + b_m s)      (params per m)
// grid = NB*32strips*NQ = 512 blocks, 256 threads.
__global__ __launch_bounds__(256, 2) void k_sweep_mfma(
    const ushort* __restrict__ gL, const ushort* __restrict__ gR,
    float* __restrict__ ws, const int mode)
{
  __shared__ ushort At[128][72];   // one K=64 chunk of 128 loop rows (+8 pad)
  __shared__ float red[2][128];
  __shared__ float gof[128], bof[128];

  const int t = threadIdx.x;
  const int w = t >> 6, l = t & 63;
  const int wm = w >> 1, wn = w & 1;
  const int ln31 = l & 31, lhi = l >> 5;

  const int b = blockIdx.x;
  const int h = b & 3, sid = b >> 2;
  const int n = sid >> 5;
  const int col0 = (sid & 31) * 128;
  const int loop0 = h * 1024;

  const size_t baseNC = (size_t)n * HW * CC;
  const ushort* __restrict__ gLn = gL + baseNC;

  // per-thread staging coordinates (fixed): chunk q_i = i*256 + t
  const int srow[4] = { (0*256+t)>>3, (1*256+t)>>3, (2*256+t)>>3, (3*256+t)>>3 };
  const int skg8[4] = { ((0*256+t)&7)*8, ((1*256+t)&7)*8, ((2*256+t)&7)*8, ((3*256+t)&7)*8 };

  // ---- issue prefetch of A-chunk 0 (tile 0, c2 0) before B-preload ----
  short8 pf[4];
  #pragma unroll
  for (int i = 0; i < 4; ++i)
    pf[i] = *(const short8*)(gLn + (size_t)(loop0 + srow[i])*CC + skg8[i]);

  // ---- preload resident (B) fragments into registers: 16 kc x 2 in ----
  // 128 rows x 64 ushorts = 1024 chunks of 8 ushorts -> 4 iters x 256 thr.
  short8 breg[16][2];
  #pragma unroll
  for (int c2 = 0; c2 < 4; ++c2) {
    __syncthreads();
    #pragma unroll
    for (int i = 0; i < 4; ++i) {
      *(short8*)&At[srow[i]][skg8[i]] =
        *(const short8*)(gR + baseNC + (size_t)(col0 + srow[i])*CC + c2*64 + skg8[i]);
    }
    __syncthreads();
    #pragma unroll
    for (int kcl = 0; kcl < 4; ++kcl)
      #pragma unroll
      for (int in = 0; in < 2; ++in)
        breg[c2*4 + kcl][in] =
          *(const short8*)&At[wn*64 + in*32 + ln31][kcl*16 + lhi*8];
  }

  // per-lane mode-1 params (indexed by resident col n)
  float aq[2], bq[2];
  if (mode == 1) {
    #pragma unroll
    for (int in = 0; in < 2; ++in) {
      const int q = col0 + wn*64 + in*32 + ln31;
      aq[in] = ws[OFF_AG   + n*HW + q];
      bq[in] = ws[OFF_BETA + n*HW + q];
    }
  }

  float runv = (mode == 1) ? 0.0f : -3.0e38f;
  f32x16 acc[2][2];

  // 8 tiles x 4 K-chunks, linearized; pf holds chunk kidx, loads for kidx+1
  // are issued before the compute barrier so their latency hides under MFMA.
  for (int kidx = 0; kidx < 32; ++kidx) {
    const int tile = kidx >> 2, c2 = kidx & 3;
    const int tile0 = loop0 + tile*128;

    if (c2 == 0) {
      #pragma unroll
      for (int im = 0; im < 2; ++im)
        #pragma unroll
        for (int in = 0; in < 2; ++in)
          #pragma unroll
          for (int e = 0; e < 16; ++e) acc[im][in][e] = 0.f;
    }

    __syncthreads();  // previous chunk's At readers (and red phase) done
    #pragma unroll
    for (int i = 0; i < 4; ++i)
      *(short8*)&At[srow[i]][skg8[i]] = pf[i];
    if (mode == 2 && c2 == 0 && t < 128) {
      gof[t] = ws[OFF_AG   + n*HW + tile0 + t];
      bof[t] = ws[OFF_BETA + n*HW + tile0 + t];
    }
    // issue next chunk's loads now; needed only after the next barrier
    if (kidx + 1 < 32) {
      const int nt0 = loop0 + ((kidx+1) >> 2)*128;
      const int nc2 = (kidx+1) & 3;
      #pragma unroll
      for (int i = 0; i < 4; ++i)
        pf[i] = *(const short8*)(gLn + (size_t)(nt0 + srow[i])*CC + nc2*64 + skg8[i]);
    }
    __syncthreads();

    #pragma unroll
    for (int kcl = 0; kcl < 4; ++kcl) {
      const short8 a0 = *(const short8*)&At[wm*64 +  0 + ln31][kcl*16 + lhi*8];
      const short8 a1 = *(const short8*)&At[wm*64 + 32 + ln31][kcl*16 + lhi*8];
      const int kc = c2*4 + kcl;
      acc[0][0] = __builtin_amdgcn_mfma_f32_32x32x16_bf16(a0, breg[kc][0], acc[0][0], 0, 0, 0);
      acc[0][1] = __builtin_amdgcn_mfma_f32_32x32x16_bf16(a0, breg[kc][1], acc[0][1], 0, 0, 0);
      acc[1][0] = __builtin_amdgcn_mfma_f32_32x32x16_bf16(a1, breg[kc][0], acc[1][0], 0, 0, 0);
      acc[1][1] = __builtin_amdgcn_mfma_f32_32x32x16_bf16(a1, breg[kc][1], acc[1][1], 0, 0, 0);
    }

    if (c2 == 3) {
      // ---- epilogue: reduce over m (rows) per n (col) ----
      // C/D layout: col = lane&31, row = (reg&3) + 8*(reg>>2) + 4*(lane>>5)
      float v[2];
      if (mode == 0) {
        #pragma unroll
        for (int in = 0; in < 2; ++in) {
          float m = -3.0e38f;
          #pragma unroll
          for (int im = 0; im < 2; ++im)
            #pragma unroll
            for (int r = 0; r < 16; ++r) m = fmaxf(m, acc[im][in][r]);
          v[in] = m;
        }
      } else if (mode == 1) {
        #pragma unroll
        for (int in = 0; in < 2; ++in) {
          float s = 0.f;
          #pragma unroll
          for (int im = 0; im < 2; ++im)
            #pragma unroll
            for (int r = 0; r < 16; ++r)
              s += __expf(fmaf(bq[in], acc[im][in][r], aq[in]));
          v[in] = s;
        }
      } else {
        #pragma unroll
        for (int in = 0; in < 2; ++in) {
          float m = -3.0e38f;
          #pragma unroll
          for (int im = 0; im < 2; ++im) {
            #pragma unroll
            for (int rg = 0; rg < 4; ++rg) {
              const int rb = wm*64 + im*32 + 4*lhi + 8*rg;
              const float4 g4 = *(const float4*)&gof[rb];
              const float4 b4 = *(const float4*)&bof[rb];
              m = fmaxf(m, fmaf(b4.x, acc[im][in][rg*4+0], g4.x));
              m = fmaxf(m, fmaf(b4.y, acc[im][in][rg*4+1], g4.y));
              m = fmaxf(m, fmaf(b4.z, acc[im][in][rg*4+2], g4.z));
              m = fmaxf(m, fmaf(b4.w, acc[im][in][rg*4+3], g4.w));
            }
          }
          v[in] = m;
        }
      }
      #pragma unroll
      for (int in = 0; in < 2; ++in) {
        const float o = __shfl_xor(v[in], 32, 64);
        v[in] = (mode == 1) ? (v[in] + o) : fmaxf(v[in], o);
      }
      if (l < 32) {
        red[wm][wn*64 +  0 + ln31] = v[0];
        red[wm][wn*64 + 32 + ln31] = v[1];
      }
      __syncthreads();
      if (t < 128) {
        if (mode == 1) runv += red[0][t] + red[1][t];
        else           runv  = fmaxf(runv, fmaxf(red[0][t], red[1][t]));
      }
      // next kidx's first __syncthreads orders red reuse
    }
  }

  if (t < 128) {
    const int base = (mode == 0) ? OFF_CMAX : ((mode == 1) ? OFF_WSUM : OFF_MAXV);
    ws[base + h*(NB*HW) + n*HW + col0 + t] = runv;
  }
}

// K4: combine colmax partials -> alpha,beta per (n,q). grid = 64
__global__ __launch_bounds__(256) void k_params(float* __restrict__ ws) {
  const int idx = blockIdx.x*256 + threadIdx.x;
  float cm = ws[OFF_CMAX + idx];
  #pragma unroll
  for (int h = 1; h < NQ; ++h) cm = fmaxf(cm, ws[OFF_CMAX + h*(NB*HW) + idx]);
  const float div   = 0.5f*(1.0f - cm);
  const float inv2d = 1.0f/(2.0f*(div + kEPS));
  ws[OFF_BETA + idx] = inv2d / kSIG;
  ws[OFF_AG   + idx] = (1.0f - inv2d) / kSIG;
}

// K6: gamma = alpha - log(Wsum + eps). grid = 64
__global__ __launch_bounds__(256) void k_gamma(float* __restrict__ ws) {
  const int idx = blockIdx.x*256 + threadIdx.x;
  float s = 0.f;
  #pragma unroll
  for (int h = 0; h < NQ; ++h) s += ws[OFF_WSUM + h*(NB*HW) + idx];
  ws[OFF_AG + idx] = ws[OFF_AG + idx] - logf(s + kEPS);
}

// K8: loss. single block.
__global__ __launch_bounds__(256) void k_final(const float* __restrict__ ws,
                                               float* __restrict__ out) {
  const int t = threadIdx.x;
  float loss = 0.f;
  for (int n = 0; n < NB; ++n) {
    float s = 0.f;
    for (int k = 0; k < 16; ++k) {
      const int idx = n*HW + k*256 + t;
      float mv = ws[OFF_MAXV + idx];
      #pragma unroll
      for (int h = 1; h < NQ; ++h) mv = fmaxf(mv, ws[OFF_MAXV + h*(NB*HW) + idx]);
      s += __expf(mv);
    }
    const float tot = blkReduceSum(s);
    loss += -logf(tot*(1.0f/4096.0f) + kEPS);
  }
  if (t == 0) out[0] = loss*0.25f;
}

extern "C" void kernel_launch(void* const* d_in, const int* in_sizes, int n_in,
                              void* d_out, int out_size, void* d_ws, size_t ws_size,
                              hipStream_t stream) {
  const float* fT = (const float*)d_in[0];
  const float* fI = (const float*)d_in[1];
  float* out = (float*)d_out;
  float* ws  = (float*)d_ws;

  const size_t need_full = (size_t)WS_FLOATS_FULL * sizeof(float);
  if (ws_size < need_full) return;  // ws measured 256 MB (R2); guard only

  const ushort* GT = (const ushort*)(ws + OFF_GT);
  const ushort* GI = (const ushort*)(ws + OFF_GI);
  k_mean      <<<256,  256, 0, stream>>>(fT, ws);
  k_norms     <<<256,  256, 0, stream>>>(fT, fI, ws);
  k_prep      <<<2048, 256, 0, stream>>>(fT, fI, ws);
  k_sweep_mfma<<<512,  256, 0, stream>>>(GT, GI, ws, 0);  // colmax
  k_params    <<<64,   256, 0, stream>>>(ws);
  k_sweep_mfma<<<512,  256, 0, stream>>>(GT, GI, ws, 1);  // Wsum
  k_gamma     <<<64,   256, 0, stream>>>(ws);
  k_sweep_mfma<<<512,  256, 0, stream>>>(GI, GT, ws, 2);  // maxv
  k_final     <<<1,    256, 0, stream>>>(ws, out);
}

// Round 9
// 244.593 us; speedup vs baseline: 1.6386x; 1.6386x over previous
//
#include <hip/hip_runtime.h>
#include <cmath>

// CXLoss MFMA pipeline, revision 9 (same logic as rev 7; symbols renamed to
// force a fresh build artifact after repeated container failures).

#define NB 4
#define CC 256
#define HW 4096
#define NQ 4   // loop-dim split per sweep (partials combined later)

static constexpr float kEPS = 1e-8f;
static constexpr float kSIG = 0.1f + 1e-8f;

typedef __attribute__((ext_vector_type(8)))  short short8;
typedef __attribute__((ext_vector_type(16))) float f32x16;

// workspace layout (float units)
enum {
  OFF_MEAN = 0,                      // 256 channel means
  OFF_INVT = 256,                    // NB*HW inv-norms (target)
  OFF_INVI = OFF_INVT + NB*HW,       // NB*HW inv-norms (input)
  OFF_BETA = OFF_INVI + NB*HW,       // NB*HW beta
  OFF_AG   = OFF_BETA + NB*HW,       // NB*HW alpha -> gamma
  OFF_CMAX = OFF_AG   + NB*HW,       // NQ*NB*HW colmax partials
  OFF_WSUM = OFF_CMAX + NQ*NB*HW,    // NQ*NB*HW Wsum partials
  OFF_MAXV = OFF_WSUM + NQ*NB*HW,    // NQ*NB*HW maxv partials
  OFF_END_SMALL = OFF_MAXV + NQ*NB*HW,
  OFF_GT = OFF_END_SMALL,            // NB*HW*CC bf16 (ushort) normalized T
  OFF_GI = OFF_GT + NB*HW*CC/2,      // NB*HW*CC bf16 (ushort) normalized I
  WS_FLOATS_FULL = OFF_GI + NB*HW*CC/2
};

__device__ __forceinline__ ushort cvt_bf16(float x) {
  unsigned u = __float_as_uint(x);
  unsigned r = (u + 0x7fffu + ((u >> 16) & 1u)) >> 16;  // round-nearest-even
  return (ushort)r;
}

__device__ __forceinline__ float blockSum256(float v) {
  __shared__ float sh[4];
  const int lane = threadIdx.x & 63, wv = threadIdx.x >> 6;
  #pragma unroll
  for (int o = 32; o > 0; o >>= 1) v += __shfl_down(v, o, 64);
  __syncthreads();
  if (lane == 0) sh[wv] = v;
  __syncthreads();
  return sh[0] + sh[1] + sh[2] + sh[3];
}

// K1: per-channel mean of featureT over (n,h,w). grid=256
__global__ __launch_bounds__(256) void k_mean2(const float* __restrict__ fT,
                                               float* __restrict__ ws) {
  const int c = blockIdx.x, t = threadIdx.x;
  float s = 0.f;
  for (int n = 0; n < NB; ++n) {
    const float* p = fT + (size_t)(n*CC + c)*HW;
    #pragma unroll
    for (int k = 0; k < 16; ++k) s += p[k*256 + t];
  }
  const float tot = blockSum256(s);
  if (t == 0) ws[OFF_MEAN + c] = tot * (1.0f/16384.0f);
}

// K2: per-pixel inverse channel-norms for both tensors. grid=256
__global__ __launch_bounds__(256) void k_norms2(const float* __restrict__ fT,
                                                const float* __restrict__ fI,
                                                float* __restrict__ ws) {
  __shared__ float sT[4][64], sI[4][64];
  const int t = threadIdx.x, q = t & 63, a = t >> 6;
  const int n = blockIdx.x >> 6;
  const int q0 = (blockIdx.x & 63) * 64;
  const float* mean = ws + OFF_MEAN;
  float accT = 0.f, accI = 0.f;
  for (int i = 0; i < 64; ++i) {
    const int c = a*64 + i;
    const float m = mean[c];
    const size_t base = (size_t)(n*CC + c)*HW + q0 + q;
    const float vT = fT[base] - m; accT += vT*vT;
    const float vI = fI[base] - m; accI += vI*vI;
  }
  sT[a][q] = accT; sI[a][q] = accI;
  __syncthreads();
  if (t < 64) {
    const float ssT = sT[0][t] + sT[1][t] + sT[2][t] + sT[3][t];
    const float ssI = sI[0][t] + sI[1][t] + sI[2][t] + sI[3][t];
    ws[OFF_INVT + n*HW + q0 + t] = 1.0f/(sqrtf(ssT) + kEPS);
    ws[OFF_INVI + n*HW + q0 + t] = 1.0f/(sqrtf(ssI) + kEPS);
  }
}

// K3: normalize + transpose both tensors to bf16 [n][p][c]. grid=2048
__global__ __launch_bounds__(256) void k_prep2(const float* __restrict__ fT,
                                               const float* __restrict__ fI,
                                               float* __restrict__ ws) {
  __shared__ float stage[64][65];    // [p][c]
  const int t = threadIdx.x;
  int bid = blockIdx.x;
  const int tensor = (bid >= 1024); bid &= 1023;
  const int n  = bid >> 8;
  const int pt = (bid & 255) >> 2;
  const int ct = bid & 3;
  const int p0 = pt * 64, c0 = ct * 64;

  const float* __restrict__ src = tensor ? fI : fT;
  const float* __restrict__ inv = ws + (tensor ? OFF_INVI : OFF_INVT);
  ushort* __restrict__ dst = (ushort*)(ws + (tensor ? OFF_GI : OFF_GT));

  const int pcol = t & 63, crb = t >> 6;
  const float invv = inv[n*HW + p0 + pcol];
  #pragma unroll
  for (int i = 0; i < 16; ++i) {
    const int cr = crb + 4*i;
    const float m = ws[OFF_MEAN + c0 + cr];
    const float v = src[((size_t)(n*CC + c0 + cr))*HW + p0 + pcol];
    stage[pcol][cr] = (v - m) * invv;
  }
  __syncthreads();
  const int cpi = t & 31, prb = t >> 5;
  #pragma unroll
  for (int j = 0; j < 8; ++j) {
    const int p = prb + 8*j;
    ushort2 u;
    u.x = cvt_bf16(stage[p][2*cpi]);
    u.y = cvt_bf16(stage[p][2*cpi + 1]);
    *(ushort2*)(dst + ((size_t)(n*HW + p0 + p))*CC + c0 + 2*cpi) = u;
  }
}

// ---------------- MFMA sweep (prefetch + STATIC breg indexing) ------------
// s[m][n] = sum_c gL[m][c]*gR[n][c]  (m = loop dim, n = resident dim)
// mode 0: colmax_q = max_m s ; mode 1: Wsum_q = sum_m exp(a_q + b_q s)
// mode 2: maxv_p = max_m (g_m + b_m s)
// grid = NB*32strips*NQ = 512 blocks, 256 threads, 2 blocks/CU.
__global__ __launch_bounds__(256, 2) void k_sweep_mfma2(
    const ushort* __restrict__ gL, const ushort* __restrict__ gR,
    float* __restrict__ ws, const int mode)
{
  __shared__ ushort At[128][72];   // K=64 chunk of 128 loop rows (+8 pad)
  __shared__ float red[2][128];
  __shared__ float gof[128], bof[128];

  const int t = threadIdx.x;
  const int w = t >> 6, l = t & 63;
  const int wm = w >> 1, wn = w & 1;
  const int ln31 = l & 31, lhi = l >> 5;

  const int b = blockIdx.x;
  const int h = b & 3, sid = b >> 2;
  const int n = sid >> 5;
  const int col0 = (sid & 31) * 128;
  const int loop0 = h * 1024;

  const size_t baseNC = (size_t)n * HW * CC;
  const ushort* __restrict__ gLn = gL + baseNC;

  // fixed per-thread staging coordinates: chunk q_i = i*256 + t
  const int srow[4] = { (0*256+t)>>3, (1*256+t)>>3, (2*256+t)>>3, (3*256+t)>>3 };
  const int skg8[4] = { ((0*256+t)&7)*8, ((1*256+t)&7)*8, ((2*256+t)&7)*8, ((3*256+t)&7)*8 };

  // prefetch A-chunk 0 before the B-preload so its latency is fully hidden
  short8 pf[4];
  #pragma unroll
  for (int i = 0; i < 4; ++i)
    pf[i] = *(const short8*)(gLn + (size_t)(loop0 + srow[i])*CC + skg8[i]);

  // preload resident (B) fragments: 16 kc x 2 in. 1024 chunks per K=64 slab.
  short8 breg[16][2];
  #pragma unroll
  for (int c2 = 0; c2 < 4; ++c2) {
    __syncthreads();
    #pragma unroll
    for (int i = 0; i < 4; ++i) {
      *(short8*)&At[srow[i]][skg8[i]] =
        *(const short8*)(gR + baseNC + (size_t)(col0 + srow[i])*CC + c2*64 + skg8[i]);
    }
    __syncthreads();
    #pragma unroll
    for (int kcl = 0; kcl < 4; ++kcl)
      #pragma unroll
      for (int in = 0; in < 2; ++in)
        breg[c2*4 + kcl][in] =
          *(const short8*)&At[wn*64 + in*32 + ln31][kcl*16 + lhi*8];
  }

  float aq[2], bq[2];   // mode-1 params per resident column
  if (mode == 1) {
    #pragma unroll
    for (int in = 0; in < 2; ++in) {
      const int q = col0 + wn*64 + in*32 + ln31;
      aq[in] = ws[OFF_AG   + n*HW + q];
      bq[in] = ws[OFF_BETA + n*HW + q];
    }
  }

  float runv = (mode == 1) ? 0.0f : -3.0e38f;

  for (int tile = 0; tile < 8; ++tile) {
    const int tile0 = loop0 + tile*128;
    f32x16 acc[2][2];
    #pragma unroll
    for (int im = 0; im < 2; ++im)
      #pragma unroll
      for (int in = 0; in < 2; ++in)
        #pragma unroll
        for (int e = 0; e < 16; ++e) acc[im][in][e] = 0.f;

    #pragma unroll
    for (int c2 = 0; c2 < 4; ++c2) {
      __syncthreads();   // prior At readers (and red phase) complete
      #pragma unroll
      for (int i = 0; i < 4; ++i)
        *(short8*)&At[srow[i]][skg8[i]] = pf[i];
      if (mode == 2 && c2 == 0 && t < 128) {
        gof[t] = ws[OFF_AG   + n*HW + tile0 + t];
        bof[t] = ws[OFF_BETA + n*HW + tile0 + t];
      }
      // issue next chunk's loads (consumed only after the next barrier);
      // c2 is unroll-static so nc2 is a compile-time constant.
      if (!(tile == 7 && c2 == 3)) {
        const int ntile0 = (c2 == 3) ? tile0 + 128 : tile0;
        const int nc2    = (c2 == 3) ? 0 : c2 + 1;
        #pragma unroll
        for (int i = 0; i < 4; ++i)
          pf[i] = *(const short8*)(gLn + (size_t)(ntile0 + srow[i])*CC + nc2*64 + skg8[i]);
      }
      __syncthreads();

      #pragma unroll
      for (int kcl = 0; kcl < 4; ++kcl) {
        const short8 a0 = *(const short8*)&At[wm*64 +  0 + ln31][kcl*16 + lhi*8];
        const short8 a1 = *(const short8*)&At[wm*64 + 32 + ln31][kcl*16 + lhi*8];
        const int kc = c2*4 + kcl;   // static index (both loops unrolled)
        acc[0][0] = __builtin_amdgcn_mfma_f32_32x32x16_bf16(a0, breg[kc][0], acc[0][0], 0, 0, 0);
        acc[0][1] = __builtin_amdgcn_mfma_f32_32x32x16_bf16(a0, breg[kc][1], acc[0][1], 0, 0, 0);
        acc[1][0] = __builtin_amdgcn_mfma_f32_32x32x16_bf16(a1, breg[kc][0], acc[1][0], 0, 0, 0);
        acc[1][1] = __builtin_amdgcn_mfma_f32_32x32x16_bf16(a1, breg[kc][1], acc[1][1], 0, 0, 0);
      }
    }

    // epilogue: reduce over m per n.
    // C/D map: col = lane&31, row = (reg&3) + 8*(reg>>2) + 4*(lane>>5)
    float v[2];
    if (mode == 0) {
      #pragma unroll
      for (int in = 0; in < 2; ++in) {
        float m = -3.0e38f;
        #pragma unroll
        for (int im = 0; im < 2; ++im)
          #pragma unroll
          for (int r = 0; r < 16; ++r) m = fmaxf(m, acc[im][in][r]);
        v[in] = m;
      }
    } else if (mode == 1) {
      #pragma unroll
      for (int in = 0; in < 2; ++in) {
        float s = 0.f;
        #pragma unroll
        for (int im = 0; im < 2; ++im)
          #pragma unroll
          for (int r = 0; r < 16; ++r)
            s += __expf(fmaf(bq[in], acc[im][in][r], aq[in]));
        v[in] = s;
      }
    } else {
      #pragma unroll
      for (int in = 0; in < 2; ++in) {
        float m = -3.0e38f;
        #pragma unroll
        for (int im = 0; im < 2; ++im) {
          #pragma unroll
          for (int rg = 0; rg < 4; ++rg) {
            const int rb = wm*64 + im*32 + 4*lhi + 8*rg;
            const float4 g4 = *(const float4*)&gof[rb];
            const float4 b4 = *(const float4*)&bof[rb];
            m = fmaxf(m, fmaf(b4.x, acc[im][in][rg*4+0], g4.x));
            m = fmaxf(m, fmaf(b4.y, acc[im][in][rg*4+1], g4.y));
            m = fmaxf(m, fmaf(b4.z, acc[im][in][rg*4+2], g4.z));
            m = fmaxf(m, fmaf(b4.w, acc[im][in][rg*4+3], g4.w));
          }
        }
        v[in] = m;
      }
    }
    #pragma unroll
    for (int in = 0; in < 2; ++in) {
      const float o = __shfl_xor(v[in], 32, 64);
      v[in] = (mode == 1) ? (v[in] + o) : fmaxf(v[in], o);
    }
    if (l < 32) {
      red[wm][wn*64 +  0 + ln31] = v[0];
      red[wm][wn*64 + 32 + ln31] = v[1];
    }
    __syncthreads();
    if (t < 128) {
      if (mode == 1) runv += red[0][t] + red[1][t];
      else           runv  = fmaxf(runv, fmaxf(red[0][t], red[1][t]));
    }
    // next tile's first __syncthreads orders red reuse
  }

  if (t < 128) {
    const int base = (mode == 0) ? OFF_CMAX : ((mode == 1) ? OFF_WSUM : OFF_MAXV);
    ws[base + h*(NB*HW) + n*HW + col0 + t] = runv;
  }
}

// K4: combine colmax partials -> alpha,beta per (n,q). grid=64
__global__ __launch_bounds__(256) void k_params2(float* __restrict__ ws) {
  const int idx = blockIdx.x*256 + threadIdx.x;
  float cm = ws[OFF_CMAX + idx];
  #pragma unroll
  for (int h = 1; h < NQ; ++h) cm = fmaxf(cm, ws[OFF_CMAX + h*(NB*HW) + idx]);
  const float div   = 0.5f*(1.0f - cm);
  const float inv2d = 1.0f/(2.0f*(div + kEPS));
  ws[OFF_BETA + idx] = inv2d / kSIG;
  ws[OFF_AG   + idx] = (1.0f - inv2d) / kSIG;
}

// K5: gamma = alpha - log(Wsum + eps). grid=64
__global__ __launch_bounds__(256) void k_gamma2(float* __restrict__ ws) {
  const int idx = blockIdx.x*256 + threadIdx.x;
  float s = 0.f;
  #pragma unroll
  for (int h = 0; h < NQ; ++h) s += ws[OFF_WSUM + h*(NB*HW) + idx];
  ws[OFF_AG + idx] = ws[OFF_AG + idx] - logf(s + kEPS);
}

// K6: final loss reduction. one block.
__global__ __launch_bounds__(256) void k_final2(const float* __restrict__ ws,
                                                float* __restrict__ out) {
  const int t = threadIdx.x;
  float loss = 0.f;
  for (int n = 0; n < NB; ++n) {
    float s = 0.f;
    for (int k = 0; k < 16; ++k) {
      const int idx = n*HW + k*256 + t;
      float mv = ws[OFF_MAXV + idx];
      #pragma unroll
      for (int h = 1; h < NQ; ++h) mv = fmaxf(mv, ws[OFF_MAXV + h*(NB*HW) + idx]);
      s += __expf(mv);
    }
    const float tot = blockSum256(s);
    loss += -logf(tot*(1.0f/4096.0f) + kEPS);
  }
  if (t == 0) out[0] = loss*0.25f;
}

extern "C" void kernel_launch(void* const* d_in, const int* in_sizes, int n_in,
                              void* d_out, int out_size, void* d_ws, size_t ws_size,
                              hipStream_t stream) {
  const float* fT = (const float*)d_in[0];
  const float* fI = (const float*)d_in[1];
  float* out = (float*)d_out;
  float* ws  = (float*)d_ws;

  const size_t need_full = (size_t)WS_FLOATS_FULL * sizeof(float);
  if (ws_size < need_full) return;  // ws measured 256 MB (R2); guard only

  const ushort* GT = (const ushort*)(ws + OFF_GT);
  const ushort* GI = (const ushort*)(ws + OFF_GI);
  k_mean2      <<<256,  256, 0, stream>>>(fT, ws);
  k_norms2     <<<256,  256, 0, stream>>>(fT, fI, ws);
  k_prep2      <<<2048, 256, 0, stream>>>(fT, fI, ws);
  k_sweep_mfma2<<<512,  256, 0, stream>>>(GT, GI, ws, 0);  // colmax
  k_params2    <<<64,   256, 0, stream>>>(ws);
  k_sweep_mfma2<<<512,  256, 0, stream>>>(GT, GI, ws, 1);  // Wsum
  k_gamma2     <<<64,   256, 0, stream>>>(ws);
  k_sweep_mfma2<<<512,  256, 0, stream>>>(GI, GT, ws, 2);  // maxv
  k_final2     <<<1,    256, 0, stream>>>(ws, out);
}